// Round 8
// baseline (374.516 us; speedup 1.0000x reference)
//
#include <hip/hip_runtime.h>
#include <hip/hip_bf16.h>

#define NCOLS 16384
#define DDIM  256
#define TILE  128            // block tile: 128 rows x 128 cols
#define NTI   128            // tiles per dim
#define BN    32             // cols per LDS sub-tile (double-buffered, 4 steps)
#define MAXCNT 1065          // max tiles per XCD band
#define SQRT_L2E 1.2011224087864498f  // sqrt(log2 e); A*B picks up log2(e)

typedef __attribute__((ext_vector_type(8))) short bf16x8;
typedef __attribute__((ext_vector_type(4))) float f32x4;
typedef __attribute__((ext_vector_type(4))) int   i32x4;

typedef __attribute__((address_space(1))) const unsigned int gu32;
typedef __attribute__((address_space(3))) unsigned int       lu32;

static __device__ __forceinline__ ushort f2bf_rne(float f) {
    unsigned u = __builtin_bit_cast(unsigned, f);
    unsigned r = (u + 0x7fffu + ((u >> 16) & 1u)) >> 16;
    return (ushort)r;
}

// ---- Kernel 1: single-pass column norm + scale + bf16 pack (transposed out).
__global__ __launch_bounds__(256)
void k_norm(const float* __restrict__ W, ushort* __restrict__ wnT,
            float* __restrict__ S) {
    __shared__ float red[8][32];
    __shared__ float scale_s[32];
    const int tid = threadIdx.x;
    const int il = tid & 31, st = tid >> 5;
    const int col = blockIdx.x * 32 + il;
    float v[32];
    float p = 0.f;
    #pragma unroll
    for (int e = 0; e < 32; ++e) {
        v[e] = W[(size_t)(st * 32 + e) * NCOLS + col];
        p = fmaf(v[e], v[e], p);
    }
    red[st][il] = p;
    __syncthreads();
    if (tid < 32) {
        float n = 0.f;
        #pragma unroll
        for (int q = 0; q < 8; ++q) n += red[q][tid];
        scale_s[tid] = SQRT_L2E / fmaxf(sqrtf(n), 1e-8f);
        S[blockIdx.x * 32 + tid] = 0.f;          // zero row-sum accumulator
    }
    __syncthreads();
    const float sc = scale_s[il];
    #pragma unroll
    for (int g = 0; g < 4; ++g) {
        union { ushort us[8]; i32x4 w4; } pk;
        #pragma unroll
        for (int e2 = 0; e2 < 8; ++e2) pk.us[e2] = f2bf_rne(v[g * 8 + e2] * sc);
        *reinterpret_cast<i32x4*>(&wnT[(size_t)col * DDIM + st * 32 + g * 8]) = pk.w4;
    }
}

// ---- Kernel 2: symmetric fused Gram + exp + row/col sums. 128x128 tiles.
// XCD-banded dispatch: XCD = bid&7 (round-robin); band x owns tile-columns
// [c0[x], c0[x+1]) of the upper triangle, walked column-by-column so each
// XCD's active B-panel (~1-2 cols x 64 KB) stays resident in its private L2.
// Block internals identical to R7 (verified absmax 0).
__global__ __launch_bounds__(256, 4)
void k_gram(const ushort* __restrict__ wnT, float* __restrict__ S) {
    __shared__ ushort Bs[2][BN * DDIM];          // 2 x 16 KiB
    __shared__ float colLDS[4][TILE];            // 2 KiB, wave-private rows

    // band bases: T(c0) for c0 = {0,45,64,78,90,101,111,120}; counts = diffs to T(128)=8256
    static const int base_t[8] = {0, 1035, 2080, 3081, 4095, 5151, 6216, 7260};
    static const int cnt_t[8]  = {1035, 1045, 1001, 1014, 1056, 1065, 1044, 996};

    const int x = blockIdx.x & 7;                // XCD id under round-robin
    const int n = blockIdx.x >> 3;               // index within this XCD's band
    if (n >= cnt_t[x]) return;                   // padding block
    const int m = base_t[x] + n;                 // global column-major triangle idx
    int tj = (int)((sqrtf(8.f * (float)m + 1.f) - 1.f) * 0.5f);
    while ((tj + 1) * (tj + 2) / 2 <= m) ++tj;
    while (tj * (tj + 1) / 2 > m) --tj;
    const int ti = m - tj * (tj + 1) / 2;        // 0..tj  (upper triangle)
    const bool diag = (ti == tj);
    const int i0 = ti * TILE, j0 = tj * TILE;

    const int tid  = threadIdx.x;
    const int lane = tid & 63, wave = tid >> 6;
    const int l15  = lane & 15;
    const int kofe = ((lane >> 4) & 3) * 8;      // k element offset (16B chunk)
    const int xorm = (lane & 7) << 4;            // read-side swizzle

    // A fragments: 2 strips x 8 k-steps, rows i0 + wave*32 + s*16 + l15
    bf16x8 afrag[2][8];
    #pragma unroll
    for (int s = 0; s < 2; ++s) {
        const ushort* arow = wnT + (size_t)(i0 + wave * 32 + s * 16 + l15) * DDIM + kofe;
        #pragma unroll
        for (int kk = 0; kk < 8; ++kk)
            afrag[s][kk] = *reinterpret_cast<const bf16x8*>(arow + kk * 32);
    }

    // stage sub-tile jt into Bs[b]: 4 insts/wave, 2 cols (512B) per inst.
    auto stage = [&](int b, int jt2) {
        #pragma unroll
        for (int q = 0; q < 4; ++q) {
            const int r0  = wave * 8 + q * 2;
            const int row = r0 + (lane >> 5);
            const int sb  = ((lane & 31) * 16) ^ ((row & 7) << 4);
            const ushort* g = wnT + (size_t)(j0 + jt2 * BN + row) * DDIM + (sb >> 1);
            char* l = (char*)&Bs[b][0] + (r0 << 9);   // wave-uniform dest
            __builtin_amdgcn_global_load_lds((gu32*)g, (lu32*)l, 16, 0, 0);
        }
    };

    float rowsum[2][4];
    float colacc[8];
    #pragma unroll
    for (int s = 0; s < 2; ++s)
        #pragma unroll
        for (int r = 0; r < 4; ++r) rowsum[s][r] = 0.f;
    #pragma unroll
    for (int c = 0; c < 8; ++c) colacc[c] = 0.f;

    stage(0, 0);
    __syncthreads();

    #pragma unroll
    for (int jt = 0; jt < 4; ++jt) {
        if (jt < 3) stage((jt + 1) & 1, jt + 1);     // prefetch overlaps compute
        const char* bufbase = (const char*)&Bs[jt & 1][0];
        #pragma unroll
        for (int jj = 0; jj < 2; ++jj) {
            const char* brow = bufbase + ((jj * 16 + l15) << 9);
            bf16x8 b[8];
            #pragma unroll
            for (int kk = 0; kk < 8; ++kk)
                b[kk] = *reinterpret_cast<const bf16x8*>(
                    brow + ((kk * 64 + kofe * 2) ^ xorm));
            __builtin_amdgcn_s_setprio(1);
            #pragma unroll
            for (int s = 0; s < 2; ++s) {
                f32x4 acc = {0.f, 0.f, 0.f, 0.f};
                #pragma unroll
                for (int kk = 0; kk < 8; ++kk)
                    acc = __builtin_amdgcn_mfma_f32_16x16x32_bf16(
                        afrag[s][kk], b[kk], acc, 0, 0, 0);
                __builtin_amdgcn_s_setprio(0);
                #pragma unroll
                for (int r = 0; r < 4; ++r) {
                    float e = __builtin_amdgcn_exp2f(acc[r]);   // = exp(G)
                    rowsum[s][r]        += e;
                    colacc[jt * 2 + jj] += e;
                }
                __builtin_amdgcn_s_setprio(1);
            }
            __builtin_amdgcn_s_setprio(0);
        }
        __syncthreads();         // staging landed + all reads of cur buf done
    }

    // row sums -> atomics (C layout: col=lane&15, row=(lane>>4)*4+r)
    #pragma unroll
    for (int s = 0; s < 2; ++s)
        #pragma unroll
        for (int r = 0; r < 4; ++r) {
            float v = rowsum[s][r];
            v += __shfl_xor(v, 1, 64);
            v += __shfl_xor(v, 2, 64);
            v += __shfl_xor(v, 4, 64);
            v += __shfl_xor(v, 8, 64);
            if (l15 == 0)
                atomicAdd(&S[i0 + wave * 32 + s * 16 + (lane >> 4) * 4 + r], v);
        }

    // mirrored col sums: wave-reduce groups, LDS combine, 1 atomic per column
    #pragma unroll
    for (int c = 0; c < 8; ++c) {
        float v = colacc[c];
        v += __shfl_xor(v, 16, 64);
        v += __shfl_xor(v, 32, 64);
        if (lane < 16) colLDS[wave][c * 16 + l15] = v;
    }
    __syncthreads();
    if (!diag && tid < TILE) {
        const float sum = colLDS[0][tid] + colLDS[1][tid] +
                          colLDS[2][tid] + colLDS[3][tid];
        atomicAdd(&S[j0 + tid], sum);
    }
}

// ---- Kernel 3: loss = lw * (ln2 * sum(log2 S) - N) / N   (the -1 folded here)
__global__ __launch_bounds__(1024)
void k_final(const float* __restrict__ S, const float* __restrict__ lw,
             float* __restrict__ out) {
    float a = 0.f;
    for (int i = threadIdx.x; i < NCOLS; i += 1024)
        a += __builtin_amdgcn_logf(S[i]);          // log2
    #pragma unroll
    for (int m2 = 1; m2 < 64; m2 <<= 1) a += __shfl_xor(a, m2, 64);
    __shared__ float red[16];
    if ((threadIdx.x & 63) == 0) red[threadIdx.x >> 6] = a;
    __syncthreads();
    if (threadIdx.x == 0) {
        float tot = 0.f;
        #pragma unroll
        for (int q2 = 0; q2 < 16; ++q2) tot += red[q2];
        out[0] = lw[0] * (tot * 0.6931471805599453f - (float)NCOLS) / (float)NCOLS;
    }
}

extern "C" void kernel_launch(void* const* d_in, const int* in_sizes, int n_in,
                              void* d_out, int out_size, void* d_ws, size_t ws_size,
                              hipStream_t stream) {
    const float* W  = (const float*)d_in[0];
    const float* lw = (const float*)d_in[1];
    float* out = (float*)d_out;

    ushort* wnT = (ushort*)d_ws;                                    // 8 MiB
    float*  S   = (float*)((char*)d_ws + (size_t)NCOLS * DDIM * 2); // 64 KiB

    k_norm <<<NCOLS / 32, 256, 0, stream>>>(W, wnT, S);
    k_gram <<<8 * MAXCNT, 256, 0, stream>>>(wnT, S);
    k_final<<<1, 1024, 0, stream>>>(S, lw, out);
}

// Round 10
// 157.963 us; speedup vs baseline: 2.3709x; 2.3709x over previous
//
#include <hip/hip_runtime.h>
#include <hip/hip_bf16.h>

#define NCOLS 16384
#define DDIM  256
#define SUBT  32             // sub-tile: 128 rows x 32 cols
#define CHUNK 43             // sub-tiles per block (516 = 12*43 per super-row)
#define GRID  768            // 64 super-rows * 12 chunks  (= 3 blocks/CU)
#define SQRT_L2E 1.2011224087864498f  // sqrt(log2 e); A*B picks up log2(e)

typedef __attribute__((ext_vector_type(8))) short bf16x8;
typedef __attribute__((ext_vector_type(4))) float f32x4;
typedef __attribute__((ext_vector_type(4))) int   i32x4;

typedef __attribute__((address_space(1))) const unsigned int gu32;
typedef __attribute__((address_space(3))) unsigned int       lu32;

static __device__ __forceinline__ ushort f2bf_rne(float f) {
    unsigned u = __builtin_bit_cast(unsigned, f);
    unsigned r = (u + 0x7fffu + ((u >> 16) & 1u)) >> 16;
    return (ushort)r;
}

// ---- Kernel 1: single-pass column norm + scale + bf16 pack (transposed out).
__global__ __launch_bounds__(256)
void k_norm(const float* __restrict__ W, ushort* __restrict__ wnT,
            float* __restrict__ S) {
    __shared__ float red[8][32];
    __shared__ float scale_s[32];
    const int tid = threadIdx.x;
    const int il = tid & 31, st = tid >> 5;
    const int col = blockIdx.x * 32 + il;
    float v[32];
    float p = 0.f;
    #pragma unroll
    for (int e = 0; e < 32; ++e) {
        v[e] = W[(size_t)(st * 32 + e) * NCOLS + col];
        p = fmaf(v[e], v[e], p);
    }
    red[st][il] = p;
    __syncthreads();
    if (tid < 32) {
        float n = 0.f;
        #pragma unroll
        for (int q = 0; q < 8; ++q) n += red[q][tid];
        scale_s[tid] = SQRT_L2E / fmaxf(sqrtf(n), 1e-8f);
        S[blockIdx.x * 32 + tid] = 0.f;          // zero row-sum accumulator
    }
    __syncthreads();
    const float sc = scale_s[il];
    #pragma unroll
    for (int g = 0; g < 4; ++g) {
        union { ushort us[8]; i32x4 w4; } pk;
        #pragma unroll
        for (int e2 = 0; e2 < 8; ++e2) pk.us[e2] = f2bf_rne(v[g * 8 + e2] * sc);
        *reinterpret_cast<i32x4*>(&wnT[(size_t)col * DDIM + st * 32 + g * 8]) = pk.w4;
    }
}

// ---- Kernel 2: symmetric Gram + exp + row/col sums, strip-sweep version.
// Super-row sr pairs row-strips {sr, 127-sr}: 516 sub-tiles, split into 12
// chunks of 43. Block sweeps its 43 sub-tiles with afrag resident (reloaded
// once if the chunk crosses the row boundary). Row sums live in registers for
// the whole sweep; col partials go to double-buffered group LDS, flushed via
// atomics every 8 sub-tiles (a full compute phase before any barrier drain).
__global__ __launch_bounds__(256, 3)
void k_gram(const ushort* __restrict__ wnT, float* __restrict__ S) {
    __shared__ ushort Bs[2][SUBT * DDIM];        // 2 x 16 KiB
    __shared__ float colLDS[2][4][256];          // 8 KiB (2 groups x 4 waves)

    const int bid = blockIdx.x;
    const int sr  = bid / 12, cch = bid - sr * 12;
    const int rowA = sr, rowB = 127 - sr;
    const int La = 512 - 4 * rowA;               // sub-tiles in row A's strip
    const int p0 = cch * CHUNK;

    const int tid  = threadIdx.x;
    const int lane = tid & 63, wave = tid >> 6;
    const int l15  = lane & 15;
    const int kq16 = ((lane >> 4) & 3) * 16;     // k-quad byte offset
    const int xorm = (lane & 7) << 4;            // read-side swizzle

    bf16x8 afrag[2][8];
    float rowsum[2][4];

    auto load_a = [&](int rowt) {
        const int i0 = rowt * 128;
        #pragma unroll
        for (int s = 0; s < 2; ++s) {
            const ushort* arow = wnT +
                (size_t)(i0 + wave * 32 + s * 16 + l15) * DDIM + (kq16 >> 1);
            #pragma unroll
            for (int kk = 0; kk < 8; ++kk)
                afrag[s][kk] = *reinterpret_cast<const bf16x8*>(arow + kk * 32);
        }
    };
    auto zero_rows = [&]() {
        #pragma unroll
        for (int s = 0; s < 2; ++s)
            #pragma unroll
            for (int r = 0; r < 4; ++r) rowsum[s][r] = 0.f;
    };
    auto flush_rows = [&](int i0) {   // C layout: col=lane&15, row=(lane>>4)*4+r
        #pragma unroll
        for (int s = 0; s < 2; ++s)
            #pragma unroll
            for (int r = 0; r < 4; ++r) {
                float v = rowsum[s][r];
                v += __shfl_xor(v, 1, 64);
                v += __shfl_xor(v, 2, 64);
                v += __shfl_xor(v, 4, 64);
                v += __shfl_xor(v, 8, 64);
                if (l15 == 0)
                    atomicAdd(&S[i0 + wave * 32 + s * 16 + (lane >> 4) * 4 + r], v);
            }
    };
    auto stage = [&](int b, int j0) {   // rule #21: linear dest, inv-swz source
        #pragma unroll
        for (int qq = 0; qq < 4; ++qq) {
            const int r0 = wave * 8 + qq * 2;
            const int rl = r0 + (lane >> 5);
            const int sb = ((lane & 31) * 16) ^ ((rl & 7) << 4);
            const ushort* g = wnT + (size_t)(j0 + rl) * DDIM + (sb >> 1);
            char* l = (char*)&Bs[b][0] + (r0 << 9);   // wave-uniform dest
            __builtin_amdgcn_global_load_lds((gu32*)g, (lu32*)l, 16, 0, 0);
        }
    };
    auto flush_group = [&](int g) {   // 8 slots x 32 cols = 256 threads
        const int slot = tid >> 5, cc = tid & 31;
        const int p = p0 + g * 8 + slot;
        if (p < p0 + CHUNK) {
            const bool inA = (p < La);
            const int prow = inA ? rowA : rowB;
            const int pk   = inA ? p : p - La;
            if (pk >= 4) {   // skip the 128x128 diagonal tile (rows-only there)
                const int o = slot * 32 + cc;
                float v = colLDS[g & 1][0][o] + colLDS[g & 1][1][o] +
                          colLDS[g & 1][2][o] + colLDS[g & 1][3][o];
                atomicAdd(&S[prow * 128 + pk * 32 + cc], v);
            }
        }
    };

    int crow = (p0 < La) ? rowA : rowB;
    load_a(crow);
    zero_rows();
    {
        const int pk0 = (p0 < La) ? p0 : p0 - La;
        stage(0, crow * 128 + pk0 * 32);
    }
    __syncthreads();

    for (int q = 0; q < CHUNK; ++q) {
        const int p = p0 + q;
        if (q > 0 && p == La) {                  // row-strip crossing (once max)
            flush_rows(rowA * 128);
            zero_rows();
            load_a(rowB);
            crow = rowB;
        }
        if (q < CHUNK - 1) {                     // prefetch next sub-tile
            const int pn = p + 1;
            const bool nA = (pn < La);
            const int nrow = nA ? rowA : rowB;
            const int nk   = nA ? pn : pn - La;
            stage((q + 1) & 1, nrow * 128 + nk * 32);
        }
        if (q >= 8 && (q & 7) == 0) flush_group((q >> 3) - 1);

        const char* bufbase = (const char*)&Bs[q & 1][0];
        const int slot = q & 7, cbuf = (q >> 3) & 1;
        float colp0 = 0.f, colp1 = 0.f;
        #pragma unroll
        for (int jj = 0; jj < 2; ++jj) {
            const char* brow = bufbase + ((jj * 16 + l15) << 9);
            bf16x8 b[8];
            #pragma unroll
            for (int kk = 0; kk < 8; ++kk)
                b[kk] = *reinterpret_cast<const bf16x8*>(
                    brow + ((kk * 64 + kq16) ^ xorm));
            __builtin_amdgcn_s_setprio(1);
            #pragma unroll
            for (int s = 0; s < 2; ++s) {
                f32x4 acc = {0.f, 0.f, 0.f, 0.f};
                #pragma unroll
                for (int kk = 0; kk < 8; ++kk)
                    acc = __builtin_amdgcn_mfma_f32_16x16x32_bf16(
                        afrag[s][kk], b[kk], acc, 0, 0, 0);
                __builtin_amdgcn_s_setprio(0);
                #pragma unroll
                for (int r = 0; r < 4; ++r) {
                    float e = __builtin_amdgcn_exp2f(acc[r]);   // = exp(G)
                    rowsum[s][r] += e;
                    if (jj == 0) colp0 += e; else colp1 += e;
                }
                __builtin_amdgcn_s_setprio(1);
            }
            __builtin_amdgcn_s_setprio(0);
        }
        // col partials: reduce over the 4 row-groups, store to group LDS
        {
            float v = colp0;
            v += __shfl_xor(v, 16, 64);
            v += __shfl_xor(v, 32, 64);
            if (lane < 16) colLDS[cbuf][wave][slot * 32 + l15] = v;
            float w = colp1;
            w += __shfl_xor(w, 16, 64);
            w += __shfl_xor(w, 32, 64);
            if (lane < 16) colLDS[cbuf][wave][slot * 32 + 16 + l15] = w;
        }
        __syncthreads();     // staging landed; colLDS group visible; buf swap
    }
    flush_group((CHUNK - 1) >> 3);               // tail group (p<p1 guarded)
    flush_rows(crow * 128);
}

// ---- Kernel 3: loss = lw * (ln2 * sum(log2 S) - N) / N   (the -1 folded here)
__global__ __launch_bounds__(1024)
void k_final(const float* __restrict__ S, const float* __restrict__ lw,
             float* __restrict__ out) {
    float a = 0.f;
    for (int i = threadIdx.x; i < NCOLS; i += 1024)
        a += __builtin_amdgcn_logf(S[i]);          // log2
    #pragma unroll
    for (int m2 = 1; m2 < 64; m2 <<= 1) a += __shfl_xor(a, m2, 64);
    __shared__ float red[16];
    if ((threadIdx.x & 63) == 0) red[threadIdx.x >> 6] = a;
    __syncthreads();
    if (threadIdx.x == 0) {
        float tot = 0.f;
        #pragma unroll
        for (int q2 = 0; q2 < 16; ++q2) tot += red[q2];
        out[0] = lw[0] * (tot * 0.6931471805599453f - (float)NCOLS) / (float)NCOLS;
    }
}

extern "C" void kernel_launch(void* const* d_in, const int* in_sizes, int n_in,
                              void* d_out, int out_size, void* d_ws, size_t ws_size,
                              hipStream_t stream) {
    const float* W  = (const float*)d_in[0];
    const float* lw = (const float*)d_in[1];
    float* out = (float*)d_out;

    ushort* wnT = (ushort*)d_ws;                                    // 8 MiB
    float*  S   = (float*)((char*)d_ws + (size_t)NCOLS * DDIM * 2); // 64 KiB

    k_norm <<<NCOLS / 32, 256, 0, stream>>>(W, wnT, S);
    k_gram <<<GRID, 256, 0, stream>>>(wnT, S);
    k_final<<<1, 1024, 0, stream>>>(S, lw, out);
}